// Round 4
// baseline (244.269 us; speedup 1.0000x reference)
//
#include <hip/hip_runtime.h>
#include <hip/hip_bf16.h>
#include <cstdint>

#define TOKENS 4096
#define DMODEL 512
#define NEXP 8
#define DFF 2048

typedef short s16x8 __attribute__((ext_vector_type(8)));
typedef short s16x4 __attribute__((ext_vector_type(4)));
typedef float f32x4 __attribute__((ext_vector_type(4)));

__device__ __forceinline__ float bf2f(short h) {
    unsigned int u = ((unsigned int)(unsigned short)h) << 16;
    return __uint_as_float(u);
}
__device__ __forceinline__ short f2bf(float f) {
    unsigned int u = __float_as_uint(f);
    u += 0x7fffu + ((u >> 16) & 1u);
    return (short)(u >> 16);
}
__device__ __forceinline__ unsigned int cvtpk_bf16(float a, float b) {
    unsigned int r;
    asm volatile("v_cvt_pk_bf16_f32 %0, %1, %2" : "=v"(r) : "v"(a), "v"(b));
    return r;
}
// tanh-form gelu via hw exp; |err| vs erf-gelu ~3e-4 absolute
__device__ __forceinline__ float gelu_f(float x) {
    float x2 = x * x;
    float z2 = x * fmaf(x2, 0.07135481627260025f, 1.5957691216057308f);
    float ex = __expf(z2);
    float r = __builtin_amdgcn_rcpf(1.0f + ex);
    return x - x * r;
}
__device__ __forceinline__ void gload_lds16(const void* g, void* l) {
    __builtin_amdgcn_global_load_lds((const __attribute__((address_space(1))) void*)g,
                                     (__attribute__((address_space(3))) void*)l, 16, 0, 0);
}

// ---------------- gate (+ x->bf16 fused): logits -> softmax -> top2 -> renorm ----------------
__global__ void gate_cvt_kernel(const float* __restrict__ x, const float* __restrict__ Wg,
                                float* __restrict__ s0, float* __restrict__ s1,
                                short* __restrict__ xb) {
    int wave = threadIdx.x >> 6;
    int lane = threadIdx.x & 63;
    int t = blockIdx.x * 4 + wave;
    const float* xr = x + (size_t)t * DMODEL + lane * 8;
    float4 xa = *(const float4*)(xr);
    float4 xv2 = *(const float4*)(xr + 4);
    float xv[8] = {xa.x, xa.y, xa.z, xa.w, xv2.x, xv2.y, xv2.z, xv2.w};
    // fused bf16 conversion of x
    s16x8 v;
#pragma unroll
    for (int j = 0; j < 8; j++) v[j] = f2bf(xv[j]);
    *(s16x8*)&xb[(size_t)t * DMODEL + lane * 8] = v;

    float lg[8];
#pragma unroll
    for (int e = 0; e < 8; e++) lg[e] = 0.f;
#pragma unroll
    for (int j = 0; j < 8; j++) {
        const float4* wr = (const float4*)(Wg + (size_t)(lane * 8 + j) * NEXP);
        float4 wa = wr[0], wb = wr[1];
        lg[0] = fmaf(xv[j], wa.x, lg[0]);
        lg[1] = fmaf(xv[j], wa.y, lg[1]);
        lg[2] = fmaf(xv[j], wa.z, lg[2]);
        lg[3] = fmaf(xv[j], wa.w, lg[3]);
        lg[4] = fmaf(xv[j], wb.x, lg[4]);
        lg[5] = fmaf(xv[j], wb.y, lg[5]);
        lg[6] = fmaf(xv[j], wb.z, lg[6]);
        lg[7] = fmaf(xv[j], wb.w, lg[7]);
    }
#pragma unroll
    for (int off = 32; off > 0; off >>= 1) {
#pragma unroll
        for (int e = 0; e < 8; e++) lg[e] += __shfl_xor(lg[e], off, 64);
    }
    float l0 = lg[0]; int i0 = 0;
#pragma unroll
    for (int e = 1; e < 8; e++) { if (lg[e] > l0) { l0 = lg[e]; i0 = e; } }
    float l1 = -3.4e38f;
#pragma unroll
    for (int e = 0; e < 8; e++) { if (e != i0 && lg[e] > l1) l1 = lg[e]; }
    float p1 = expf(l1 - l0);
    float sa = 1.0f / (1.0f + p1);
    if (lane == 0) { s0[t] = sa; s1[t] = p1 * sa; }
}

// ---- batched transpose + f32->bf16: in[b][R][C] -> out[b][C][R], tile 32r x 64c ----
__global__ void transpose_cvt_kernel(const float* __restrict__ in, short* __restrict__ out,
                                     int R, int C) {
    __shared__ float t[64][33];
    int b = blockIdx.z;
    const float* ip = in + (size_t)b * R * C;
    short* op = out + (size_t)b * R * C;
    int c0 = blockIdx.x * 64, r0 = blockIdx.y * 32;
    int tid = threadIdx.x;
    int lr = tid >> 3, lc8 = (tid & 7) * 8;
    const float* src = &ip[(size_t)(r0 + lr) * C + c0 + lc8];
    float4 v0 = *(const float4*)src;
    float4 v1 = *(const float4*)(src + 4);
    t[lc8 + 0][lr] = v0.x; t[lc8 + 1][lr] = v0.y; t[lc8 + 2][lr] = v0.z; t[lc8 + 3][lr] = v0.w;
    t[lc8 + 4][lr] = v1.x; t[lc8 + 5][lr] = v1.y; t[lc8 + 6][lr] = v1.z; t[lc8 + 7][lr] = v1.w;
    __syncthreads();
    int sc = tid >> 2, sk = (tid & 3) * 8;
    s16x8 o;
#pragma unroll
    for (int j = 0; j < 8; j++) o[j] = f2bf(t[sc][sk + j]);
    *(s16x8*)&op[(size_t)(c0 + sc) * R + r0 + sk] = o;
}

// ---------------- GEMM1: Y[e] = x_bf16 @ W1[e]  (A[M,K] x BT[N,K]) ----------------
__launch_bounds__(256, 2)
__global__ void gemm1_kernel(const short* __restrict__ xb, const short* __restrict__ w1t,
                             short* __restrict__ Y) {
    __shared__ short Al[128 * 64];
    __shared__ short Bl[128 * 64];
    int d = blockIdx.x;
    int e = d & 7;
    int tno = d >> 3;
    int n0 = (tno & 15) * 128;
    int m0 = (tno >> 4) * 128;
    const short* A = xb;
    const short* B = w1t + (size_t)e * DFF * DMODEL;
    short* Yo = Y + (size_t)e * TOKENS * DFF;

    int tid = threadIdx.x;
    int lane = tid & 63;
    int w = tid >> 6;
    int m_off = (w >> 1) * 64;
    int n_off = (w & 1) * 64;

    int srow = lane >> 3;
    int schunk = (lane & 7) ^ srow;
    int q = lane >> 4;

    f32x4 acc[4][4];
#pragma unroll
    for (int mi = 0; mi < 4; mi++)
#pragma unroll
        for (int ni = 0; ni < 4; ni++) acc[mi][ni] = (f32x4){0.f, 0.f, 0.f, 0.f};

    for (int k0 = 0; k0 < DMODEL; k0 += 64) {
#pragma unroll
        for (int c = 0; c < 4; c++) {
            int seg = c * 4 + w;
            gload_lds16(&A[(size_t)(m0 + seg * 8 + srow) * DMODEL + k0 + schunk * 8],
                        &Al[seg * 512]);
            gload_lds16(&B[(size_t)(n0 + seg * 8 + srow) * DMODEL + k0 + schunk * 8],
                        &Bl[seg * 512]);
        }
        __syncthreads();
#pragma unroll
        for (int ks = 0; ks < 2; ks++) {
            s16x8 af[4], bfr[4];
#pragma unroll
            for (int mi = 0; mi < 4; mi++) {
                int r = m_off + mi * 16 + (lane & 15);
                int cp = (ks * 4 + q) ^ (r & 7);
                af[mi] = *(const s16x8*)&Al[r * 64 + cp * 8];
            }
#pragma unroll
            for (int ni = 0; ni < 4; ni++) {
                int r = n_off + ni * 16 + (lane & 15);
                int cp = (ks * 4 + q) ^ (r & 7);
                bfr[ni] = *(const s16x8*)&Bl[r * 64 + cp * 8];
            }
#pragma unroll
            for (int mi = 0; mi < 4; mi++)
#pragma unroll
                for (int ni = 0; ni < 4; ni++)
                    acc[mi][ni] = __builtin_amdgcn_mfma_f32_16x16x32_bf16(af[mi], bfr[ni], acc[mi][ni], 0, 0, 0);
        }
        __syncthreads();
    }
#pragma unroll
    for (int mi = 0; mi < 4; mi++)
#pragma unroll
        for (int ni = 0; ni < 4; ni++) {
            int row = m0 + m_off + mi * 16 + (lane >> 4) * 4;
            int col = n0 + n_off + ni * 16 + (lane & 15);
#pragma unroll
            for (int r = 0; r < 4; r++)
                Yo[(size_t)(row + r) * DFF + col] = f2bf(acc[mi][ni][r]);
        }
}

// ------- GEMM2: part[e] = (gelu(s0*Y+b1)+gelu(s1*Y+b1)) @ W2 -------
// BM=64, BN=512, BK=32; double-buffered Bl/Hs, ONE barrier per phase;
// phase body: [stage Bl(next) async + load Y(next)] -> MFMA(cur) -> H-compute(next) -> barrier.
__launch_bounds__(512, 4)
__global__ void gemm2_kernel(const short* __restrict__ Y, const short* __restrict__ w2t,
                             const float* __restrict__ s0v, const float* __restrict__ s1v,
                             const float* __restrict__ b1, float* __restrict__ part) {
    __shared__ short Bl[2][512 * 32];   // 64KB
    __shared__ short Hs[2][64 * 32];    // 8KB
    int d = blockIdx.x;
    int e = d & 7;                      // expert -> XCD pin
    int m0 = (d >> 3) * 64;
    const short* Ye = Y + (size_t)e * TOKENS * DFF;
    const short* B = w2t + (size_t)e * DMODEL * DFF;   // [512][2048] = W2^T
    const float* b1e = b1 + (size_t)e * DFF;
    float* Pe = part + (size_t)e * TOKENS * DMODEL;

    int tid = threadIdx.x;
    int lane = tid & 63;
    int w = tid >> 6;                // 0..7
    int n_off = w * 64;
    int q = lane >> 4;

    // H lane constants: 4 y-elems per thread (64 rows x 32 cols per phase)
    int hrow = tid >> 3;             // 0..63
    int off8 = tid & 7;
    int hcol = off8 * 4;
    int hchunk16 = off8 >> 1, hsub = off8 & 1;
    int hcp = hchunk16 ^ ((hrow >> 1) & 3);
    int hoff_bytes = hrow * 64 + hcp * 16 + hsub * 8;
    float sa = s0v[m0 + hrow], sb = s1v[m0 + hrow];
    const short* yrow = &Ye[(size_t)(m0 + hrow) * DFF + hcol];

    // Bl staging lane constants: seg covers 16 rows x 64B
    int brow = lane >> 2;
    int bsrc = (lane & 3) ^ ((lane >> 3) & 3);

    f32x4 acc[4][4];
#pragma unroll
    for (int mi = 0; mi < 4; mi++)
#pragma unroll
        for (int ni = 0; ni < 4; ni++) acc[mi][ni] = (f32x4){0.f, 0.f, 0.f, 0.f};

    // ---- prologue: buffer 0 ----
#pragma unroll
    for (int c = 0; c < 4; c++) {
        int seg = c * 8 + w;
        gload_lds16(&B[(size_t)(seg * 16 + brow) * DFF + bsrc * 8], &Bl[0][seg * 512]);
    }
    {
        s16x4 yv = *(const s16x4*)yrow;
        float4 bb = *(const float4*)&b1e[hcol];
        float bbv[4] = {bb.x, bb.y, bb.z, bb.w};
        float hs4[4];
#pragma unroll
        for (int j = 0; j < 4; j++) {
            float yf = bf2f(yv[j]);
            hs4[j] = gelu_f(fmaf(sa, yf, bbv[j])) + gelu_f(fmaf(sb, yf, bbv[j]));
        }
        unsigned int* hd = (unsigned int*)((char*)&Hs[0][0] + hoff_bytes);
        hd[0] = cvtpk_bf16(hs4[0], hs4[1]);
        hd[1] = cvtpk_bf16(hs4[2], hs4[3]);
    }
    __syncthreads();

    const int NT = DFF / 32;   // 64 phases
    for (int f = 0; f < NT; f++) {
        int cur = f & 1;
        const short* Blc = &Bl[cur][0];
        const short* Hsc = &Hs[cur][0];
        s16x4 yn;
        float4 bn;
        bool more = (f + 1 < NT);
        if (more) {
            int f1 = (f + 1) * 32;
#pragma unroll
            for (int c = 0; c < 4; c++) {
                int seg = c * 8 + w;
                gload_lds16(&B[(size_t)(seg * 16 + brow) * DFF + f1 + bsrc * 8],
                            &Bl[cur ^ 1][seg * 512]);
            }
            yn = *(const s16x4*)(yrow + f1);
            bn = *(const float4*)&b1e[f1 + hcol];
        }
        // MFMA on current buffers (matrix pipe) — overlaps with H VALU below
        {
            s16x8 af[4];
#pragma unroll
            for (int mi = 0; mi < 4; mi++) {
                int r = mi * 16 + (lane & 15);
                int cp = q ^ ((r >> 1) & 3);
                af[mi] = *(const s16x8*)&Hsc[r * 32 + cp * 8];
            }
#pragma unroll
            for (int ni = 0; ni < 4; ni++) {
                int r = n_off + ni * 16 + (lane & 15);
                int cp = q ^ ((r >> 1) & 3);
                s16x8 bfr = *(const s16x8*)&Blc[r * 32 + cp * 8];
#pragma unroll
                for (int mi = 0; mi < 4; mi++)
                    acc[mi][ni] = __builtin_amdgcn_mfma_f32_16x16x32_bf16(af[mi], bfr, acc[mi][ni], 0, 0, 0);
            }
        }
        if (more) {
            float bbv[4] = {bn.x, bn.y, bn.z, bn.w};
            float hs4[4];
#pragma unroll
            for (int j = 0; j < 4; j++) {
                float yf = bf2f(yn[j]);
                hs4[j] = gelu_f(fmaf(sa, yf, bbv[j])) + gelu_f(fmaf(sb, yf, bbv[j]));
            }
            unsigned int* hd = (unsigned int*)((char*)&Hs[cur ^ 1][0] + hoff_bytes);
            hd[0] = cvtpk_bf16(hs4[0], hs4[1]);
            hd[1] = cvtpk_bf16(hs4[2], hs4[3]);
        }
        __syncthreads();
    }

#pragma unroll
    for (int mi = 0; mi < 4; mi++)
#pragma unroll
        for (int ni = 0; ni < 4; ni++) {
            int row = m0 + mi * 16 + (lane >> 4) * 4;
            int col = n_off + ni * 16 + (lane & 15);
#pragma unroll
            for (int r = 0; r < 4; r++)
                Pe[(size_t)(row + r) * DMODEL + col] = acc[mi][ni][r];
        }
}

// ---------------- reduce over experts + 2*b2_sum ----------------
__global__ void reduce_kernel(const float* __restrict__ part, const float* __restrict__ b2,
                              float* __restrict__ out) {
    int i = (blockIdx.x * 256 + threadIdx.x) * 4;
    if (i >= TOKENS * DMODEL) return;
    int n = i & (DMODEL - 1);
    float4 s = {0.f, 0.f, 0.f, 0.f};
    float4 bs = {0.f, 0.f, 0.f, 0.f};
#pragma unroll
    for (int e = 0; e < 8; e++) {
        float4 p = *(const float4*)&part[(size_t)e * TOKENS * DMODEL + i];
        s.x += p.x; s.y += p.y; s.z += p.z; s.w += p.w;
        float4 b = *(const float4*)&b2[(size_t)e * DMODEL + n];
        bs.x += b.x; bs.y += b.y; bs.z += b.z; bs.w += b.w;
    }
    s.x += 2.f * bs.x; s.y += 2.f * bs.y; s.z += 2.f * bs.z; s.w += 2.f * bs.w;
    *(float4*)&out[i] = s;
}

extern "C" void kernel_launch(void* const* d_in, const int* in_sizes, int n_in,
                              void* d_out, int out_size, void* d_ws, size_t ws_size,
                              hipStream_t stream) {
    const float* x  = (const float*)d_in[0];
    const float* Wg = (const float*)d_in[1];
    const float* W1 = (const float*)d_in[2];
    const float* b1 = (const float*)d_in[3];
    const float* W2 = (const float*)d_in[4];
    const float* b2 = (const float*)d_in[5];
    float* out = (float*)d_out;

    char* ws = (char*)d_ws;
    float* s0  = (float*)(ws);
    float* s1  = (float*)(ws + 16384);
    short* xb  = (short*)(ws + 32768);
    short* w1t = (short*)(ws + 32768 + 4194304);
    short* w2t = (short*)(ws + 32768 + 4194304 + 16777216);
    short* Yb  = (short*)(ws + 32768 + 4194304 + 2ull * 16777216);
    float* part= (float*)(ws + 32768 + 4194304 + 2ull * 16777216 + 134217728);

    hipLaunchKernelGGL(gate_cvt_kernel, dim3(1024), dim3(256), 0, stream, x, Wg, s0, s1, xb);
    hipLaunchKernelGGL(transpose_cvt_kernel, dim3(32, 16, 8), dim3(256), 0, stream, W1, w1t, 512, 2048);
    hipLaunchKernelGGL(transpose_cvt_kernel, dim3(8, 64, 8), dim3(256), 0, stream, W2, w2t, 2048, 512);
    hipLaunchKernelGGL(gemm1_kernel, dim3(4096), dim3(256), 0, stream, xb, w1t, Yb);
    hipLaunchKernelGGL(gemm2_kernel, dim3(512), dim3(512), 0, stream, Yb, w2t, s0, s1, b1, part);
    hipLaunchKernelGGL(reduce_kernel, dim3(2048), dim3(256), 0, stream, part, b2, out);
}

// Round 5
// 238.361 us; speedup vs baseline: 1.0248x; 1.0248x over previous
//
#include <hip/hip_runtime.h>
#include <hip/hip_bf16.h>
#include <cstdint>

#define TOKENS 4096
#define DMODEL 512
#define NEXP 8
#define DFF 2048

typedef short s16x8 __attribute__((ext_vector_type(8)));
typedef short s16x4 __attribute__((ext_vector_type(4)));
typedef float f32x4 __attribute__((ext_vector_type(4)));

__device__ __forceinline__ float bf2f(short h) {
    unsigned int u = ((unsigned int)(unsigned short)h) << 16;
    return __uint_as_float(u);
}
__device__ __forceinline__ short f2bf(float f) {
    unsigned int u = __float_as_uint(f);
    u += 0x7fffu + ((u >> 16) & 1u);
    return (short)(u >> 16);
}
// tanh-form gelu via hw exp; |err| vs erf-gelu ~3e-4 absolute
__device__ __forceinline__ float gelu_f(float x) {
    float x2 = x * x;
    float z2 = x * fmaf(x2, 0.07135481627260025f, 1.5957691216057308f);
    float ex = __expf(z2);
    float r = __builtin_amdgcn_rcpf(1.0f + ex);
    return x - x * r;
}
__device__ __forceinline__ void gload_lds16(const void* g, void* l) {
    __builtin_amdgcn_global_load_lds((const __attribute__((address_space(1))) void*)g,
                                     (__attribute__((address_space(3))) void*)l, 16, 0, 0);
}

// ---------------- gate (+ x->bf16 fused): logits -> softmax -> top2 -> renorm ----------------
__global__ void gate_cvt_kernel(const float* __restrict__ x, const float* __restrict__ Wg,
                                float* __restrict__ s0, float* __restrict__ s1,
                                short* __restrict__ xb) {
    int wave = threadIdx.x >> 6;
    int lane = threadIdx.x & 63;
    int t = blockIdx.x * 4 + wave;
    const float* xr = x + (size_t)t * DMODEL + lane * 8;
    float4 xa = *(const float4*)(xr);
    float4 xv2 = *(const float4*)(xr + 4);
    float xv[8] = {xa.x, xa.y, xa.z, xa.w, xv2.x, xv2.y, xv2.z, xv2.w};
    s16x8 v;
#pragma unroll
    for (int j = 0; j < 8; j++) v[j] = f2bf(xv[j]);
    *(s16x8*)&xb[(size_t)t * DMODEL + lane * 8] = v;

    float lg[8];
#pragma unroll
    for (int e = 0; e < 8; e++) lg[e] = 0.f;
#pragma unroll
    for (int j = 0; j < 8; j++) {
        const float4* wr = (const float4*)(Wg + (size_t)(lane * 8 + j) * NEXP);
        float4 wa = wr[0], wb = wr[1];
        lg[0] = fmaf(xv[j], wa.x, lg[0]);
        lg[1] = fmaf(xv[j], wa.y, lg[1]);
        lg[2] = fmaf(xv[j], wa.z, lg[2]);
        lg[3] = fmaf(xv[j], wa.w, lg[3]);
        lg[4] = fmaf(xv[j], wb.x, lg[4]);
        lg[5] = fmaf(xv[j], wb.y, lg[5]);
        lg[6] = fmaf(xv[j], wb.z, lg[6]);
        lg[7] = fmaf(xv[j], wb.w, lg[7]);
    }
#pragma unroll
    for (int off = 32; off > 0; off >>= 1) {
#pragma unroll
        for (int e = 0; e < 8; e++) lg[e] += __shfl_xor(lg[e], off, 64);
    }
    float l0 = lg[0]; int i0 = 0;
#pragma unroll
    for (int e = 1; e < 8; e++) { if (lg[e] > l0) { l0 = lg[e]; i0 = e; } }
    float l1 = -3.4e38f;
#pragma unroll
    for (int e = 0; e < 8; e++) { if (e != i0 && lg[e] > l1) l1 = lg[e]; }
    float p1 = expf(l1 - l0);
    float sa = 1.0f / (1.0f + p1);
    if (lane == 0) { s0[t] = sa; s1[t] = p1 * sa; }
}

// ---- batched transpose + f32->bf16: in[b][R][C] -> out[b][C][R], tile 32r x 64c ----
__global__ void transpose_cvt_kernel(const float* __restrict__ in, short* __restrict__ out,
                                     int R, int C) {
    __shared__ float t[64][33];
    int b = blockIdx.z;
    const float* ip = in + (size_t)b * R * C;
    short* op = out + (size_t)b * R * C;
    int c0 = blockIdx.x * 64, r0 = blockIdx.y * 32;
    int tid = threadIdx.x;
    int lr = tid >> 3, lc8 = (tid & 7) * 8;
    const float* src = &ip[(size_t)(r0 + lr) * C + c0 + lc8];
    float4 v0 = *(const float4*)src;
    float4 v1 = *(const float4*)(src + 4);
    t[lc8 + 0][lr] = v0.x; t[lc8 + 1][lr] = v0.y; t[lc8 + 2][lr] = v0.z; t[lc8 + 3][lr] = v0.w;
    t[lc8 + 4][lr] = v1.x; t[lc8 + 5][lr] = v1.y; t[lc8 + 6][lr] = v1.z; t[lc8 + 7][lr] = v1.w;
    __syncthreads();
    int sc = tid >> 2, sk = (tid & 3) * 8;
    s16x8 o;
#pragma unroll
    for (int j = 0; j < 8; j++) o[j] = f2bf(t[sc][sk + j]);
    *(s16x8*)&op[(size_t)(c0 + sc) * R + r0 + sk] = o;
}

// ---- GEMM1 + fused activation: H[e] = gelu(s0*(x@W1[e])+b1) + gelu(s1*(x@W1[e])+b1) ----
__launch_bounds__(256, 2)
__global__ void gemm1_kernel(const short* __restrict__ xb, const short* __restrict__ w1t,
                             const float* __restrict__ s0v, const float* __restrict__ s1v,
                             const float* __restrict__ b1, short* __restrict__ H) {
    __shared__ short Al[128 * 64];
    __shared__ short Bl[128 * 64];
    __shared__ float ls0[128], ls1[128], lb1[128];
    int d = blockIdx.x;
    int e = d & 7;
    int tno = d >> 3;
    int n0 = (tno & 15) * 128;
    int m0 = (tno >> 4) * 128;
    const short* A = xb;
    const short* B = w1t + (size_t)e * DFF * DMODEL;
    short* Ho = H + (size_t)e * TOKENS * DFF;

    int tid = threadIdx.x;
    int lane = tid & 63;
    int w = tid >> 6;
    int m_off = (w >> 1) * 64;
    int n_off = (w & 1) * 64;

    if (tid < 128) {
        ls0[tid] = s0v[m0 + tid];
        ls1[tid] = s1v[m0 + tid];
        lb1[tid] = b1[(size_t)e * DFF + n0 + tid];
    }

    int srow = lane >> 3;
    int schunk = (lane & 7) ^ srow;
    int q = lane >> 4;

    f32x4 acc[4][4];
#pragma unroll
    for (int mi = 0; mi < 4; mi++)
#pragma unroll
        for (int ni = 0; ni < 4; ni++) acc[mi][ni] = (f32x4){0.f, 0.f, 0.f, 0.f};

    for (int k0 = 0; k0 < DMODEL; k0 += 64) {
#pragma unroll
        for (int c = 0; c < 4; c++) {
            int seg = c * 4 + w;
            gload_lds16(&A[(size_t)(m0 + seg * 8 + srow) * DMODEL + k0 + schunk * 8],
                        &Al[seg * 512]);
            gload_lds16(&B[(size_t)(n0 + seg * 8 + srow) * DMODEL + k0 + schunk * 8],
                        &Bl[seg * 512]);
        }
        __syncthreads();
#pragma unroll
        for (int ks = 0; ks < 2; ks++) {
            s16x8 af[4], bfr[4];
#pragma unroll
            for (int mi = 0; mi < 4; mi++) {
                int r = m_off + mi * 16 + (lane & 15);
                int cp = (ks * 4 + q) ^ (r & 7);
                af[mi] = *(const s16x8*)&Al[r * 64 + cp * 8];
            }
#pragma unroll
            for (int ni = 0; ni < 4; ni++) {
                int r = n_off + ni * 16 + (lane & 15);
                int cp = (ks * 4 + q) ^ (r & 7);
                bfr[ni] = *(const s16x8*)&Bl[r * 64 + cp * 8];
            }
#pragma unroll
            for (int mi = 0; mi < 4; mi++)
#pragma unroll
                for (int ni = 0; ni < 4; ni++)
                    acc[mi][ni] = __builtin_amdgcn_mfma_f32_16x16x32_bf16(af[mi], bfr[ni], acc[mi][ni], 0, 0, 0);
        }
        __syncthreads();
    }
    // epilogue: fused dual-gelu on f32 accumulators
#pragma unroll
    for (int mi = 0; mi < 4; mi++) {
        int rl = m_off + mi * 16 + (lane >> 4) * 4;
        float sa4[4], sb4[4];
#pragma unroll
        for (int r = 0; r < 4; r++) { sa4[r] = ls0[rl + r]; sb4[r] = ls1[rl + r]; }
#pragma unroll
        for (int ni = 0; ni < 4; ni++) {
            int cl = n_off + ni * 16 + (lane & 15);
            float bb = lb1[cl];
#pragma unroll
            for (int r = 0; r < 4; r++) {
                float a = acc[mi][ni][r];
                float h = gelu_f(fmaf(sa4[r], a, bb)) + gelu_f(fmaf(sb4[r], a, bb));
                Ho[(size_t)(m0 + rl + r) * DFF + n0 + cl] = f2bf(h);
            }
        }
    }
}

// ------- GEMM2 (pure): part[e] = H[e] @ W2[e]  (BM=64, BN=512, BK=32, 8 waves) -------
__launch_bounds__(512, 4)
__global__ void gemm2_kernel(const short* __restrict__ H, const short* __restrict__ w2t,
                             float* __restrict__ part) {
    __shared__ short Al[64 * 32];    // 4KB
    __shared__ short Bl[512 * 32];   // 32KB
    int d = blockIdx.x;
    int e = d & 7;                   // expert -> XCD pin
    int m0 = (d >> 3) * 64;
    const short* A = H + (size_t)e * TOKENS * DFF;
    const short* B = w2t + (size_t)e * DMODEL * DFF;   // [512][2048] = W2^T
    float* Pe = part + (size_t)e * TOKENS * DMODEL;

    int tid = threadIdx.x;
    int lane = tid & 63;
    int w = tid >> 6;                // 0..7
    int n_off = w * 64;
    int q = lane >> 4;

    // staging lane constants: seg covers 16 rows x 64B; 64B rows swizzle (row>>1)&3
    int srow = lane >> 2;
    int schunk = (lane & 3) ^ ((lane >> 3) & 3);

    f32x4 acc[4][4];
#pragma unroll
    for (int mi = 0; mi < 4; mi++)
#pragma unroll
        for (int ni = 0; ni < 4; ni++) acc[mi][ni] = (f32x4){0.f, 0.f, 0.f, 0.f};

    for (int f0 = 0; f0 < DFF; f0 += 32) {
#pragma unroll
        for (int c = 0; c < 4; c++) {
            int seg = c * 8 + w;     // 0..31, wave-uniform
            gload_lds16(&B[(size_t)(seg * 16 + srow) * DFF + f0 + schunk * 8],
                        &Bl[seg * 512]);
        }
        if (w < 4) {                 // A tile: 4 segs of 16 rows
            gload_lds16(&A[(size_t)(m0 + w * 16 + srow) * DFF + f0 + schunk * 8],
                        &Al[w * 512]);
        }
        __syncthreads();
        {
            s16x8 af[4];
#pragma unroll
            for (int mi = 0; mi < 4; mi++) {
                int r = mi * 16 + (lane & 15);
                int cp = q ^ ((r >> 1) & 3);
                af[mi] = *(const s16x8*)&Al[r * 32 + cp * 8];
            }
#pragma unroll
            for (int ni = 0; ni < 4; ni++) {
                int r = n_off + ni * 16 + (lane & 15);
                int cp = q ^ ((r >> 1) & 3);
                s16x8 bfr = *(const s16x8*)&Bl[r * 32 + cp * 8];
#pragma unroll
                for (int mi = 0; mi < 4; mi++)
                    acc[mi][ni] = __builtin_amdgcn_mfma_f32_16x16x32_bf16(af[mi], bfr, acc[mi][ni], 0, 0, 0);
            }
        }
        __syncthreads();
    }

#pragma unroll
    for (int mi = 0; mi < 4; mi++)
#pragma unroll
        for (int ni = 0; ni < 4; ni++) {
            int row = m0 + mi * 16 + (lane >> 4) * 4;
            int col = n_off + ni * 16 + (lane & 15);
#pragma unroll
            for (int r = 0; r < 4; r++)
                Pe[(size_t)(row + r) * DMODEL + col] = acc[mi][ni][r];
        }
}

// ---------------- reduce over experts + 2*b2_sum ----------------
__global__ void reduce_kernel(const float* __restrict__ part, const float* __restrict__ b2,
                              float* __restrict__ out) {
    int i = (blockIdx.x * 256 + threadIdx.x) * 4;
    if (i >= TOKENS * DMODEL) return;
    int n = i & (DMODEL - 1);
    float4 s = {0.f, 0.f, 0.f, 0.f};
    float4 bs = {0.f, 0.f, 0.f, 0.f};
#pragma unroll
    for (int e = 0; e < 8; e++) {
        float4 p = *(const float4*)&part[(size_t)e * TOKENS * DMODEL + i];
        s.x += p.x; s.y += p.y; s.z += p.z; s.w += p.w;
        float4 b = *(const float4*)&b2[(size_t)e * DMODEL + n];
        bs.x += b.x; bs.y += b.y; bs.z += b.z; bs.w += b.w;
    }
    s.x += 2.f * bs.x; s.y += 2.f * bs.y; s.z += 2.f * bs.z; s.w += 2.f * bs.w;
    *(float4*)&out[i] = s;
}

extern "C" void kernel_launch(void* const* d_in, const int* in_sizes, int n_in,
                              void* d_out, int out_size, void* d_ws, size_t ws_size,
                              hipStream_t stream) {
    const float* x  = (const float*)d_in[0];
    const float* Wg = (const float*)d_in[1];
    const float* W1 = (const float*)d_in[2];
    const float* b1 = (const float*)d_in[3];
    const float* W2 = (const float*)d_in[4];
    const float* b2 = (const float*)d_in[5];
    float* out = (float*)d_out;

    char* ws = (char*)d_ws;
    float* s0  = (float*)(ws);
    float* s1  = (float*)(ws + 16384);
    short* xb  = (short*)(ws + 32768);
    short* w1t = (short*)(ws + 32768 + 4194304);
    short* w2t = (short*)(ws + 32768 + 4194304 + 16777216);
    short* Hb  = (short*)(ws + 32768 + 4194304 + 2ull * 16777216);              // 128MB [e][4096][2048]
    float* part= (float*)(ws + 32768 + 4194304 + 2ull * 16777216 + 134217728);  // 64MB

    hipLaunchKernelGGL(gate_cvt_kernel, dim3(1024), dim3(256), 0, stream, x, Wg, s0, s1, xb);
    hipLaunchKernelGGL(transpose_cvt_kernel, dim3(32, 16, 8), dim3(256), 0, stream, W1, w1t, 512, 2048);
    hipLaunchKernelGGL(transpose_cvt_kernel, dim3(8, 64, 8), dim3(256), 0, stream, W2, w2t, 2048, 512);
    hipLaunchKernelGGL(gemm1_kernel, dim3(4096), dim3(256), 0, stream, xb, w1t, s0, s1, b1, Hb);
    hipLaunchKernelGGL(gemm2_kernel, dim3(512), dim3(512), 0, stream, Hb, w2t, part);
    hipLaunchKernelGGL(reduce_kernel, dim3(2048), dim3(256), 0, stream, part, b2, out);
}

// Round 6
// 210.365 us; speedup vs baseline: 1.1612x; 1.1331x over previous
//
#include <hip/hip_runtime.h>
#include <hip/hip_bf16.h>
#include <cstdint>

#define TOKENS 4096
#define DMODEL 512
#define NEXP 8
#define DFF 2048

typedef short s16x8 __attribute__((ext_vector_type(8)));
typedef short s16x4 __attribute__((ext_vector_type(4)));
typedef float f32x4 __attribute__((ext_vector_type(4)));

__device__ __forceinline__ float bf2f(short h) {
    unsigned int u = ((unsigned int)(unsigned short)h) << 16;
    return __uint_as_float(u);
}
__device__ __forceinline__ short f2bf(float f) {
    unsigned int u = __float_as_uint(f);
    u += 0x7fffu + ((u >> 16) & 1u);
    return (short)(u >> 16);
}
// tanh-form gelu via hw exp; |err| vs erf-gelu ~3e-4 absolute
__device__ __forceinline__ float gelu_f(float x) {
    float x2 = x * x;
    float z2 = x * fmaf(x2, 0.07135481627260025f, 1.5957691216057308f);
    float ex = __expf(z2);
    float r = __builtin_amdgcn_rcpf(1.0f + ex);
    return x - x * r;
}
__device__ __forceinline__ void gload_lds16(const void* g, void* l) {
    __builtin_amdgcn_global_load_lds((const __attribute__((address_space(1))) void*)g,
                                     (__attribute__((address_space(3))) void*)l, 16, 0, 0);
}

// ---------------- gate (+ x->bf16 fused): logits -> softmax -> top2 -> renorm ----------------
__global__ void gate_cvt_kernel(const float* __restrict__ x, const float* __restrict__ Wg,
                                float* __restrict__ s0, float* __restrict__ s1,
                                short* __restrict__ xb) {
    int wave = threadIdx.x >> 6;
    int lane = threadIdx.x & 63;
    int t = blockIdx.x * 4 + wave;
    const float* xr = x + (size_t)t * DMODEL + lane * 8;
    float4 xa = *(const float4*)(xr);
    float4 xv2 = *(const float4*)(xr + 4);
    float xv[8] = {xa.x, xa.y, xa.z, xa.w, xv2.x, xv2.y, xv2.z, xv2.w};
    s16x8 v;
#pragma unroll
    for (int j = 0; j < 8; j++) v[j] = f2bf(xv[j]);
    *(s16x8*)&xb[(size_t)t * DMODEL + lane * 8] = v;

    float lg[8];
#pragma unroll
    for (int e = 0; e < 8; e++) lg[e] = 0.f;
#pragma unroll
    for (int j = 0; j < 8; j++) {
        const float4* wr = (const float4*)(Wg + (size_t)(lane * 8 + j) * NEXP);
        float4 wa = wr[0], wb = wr[1];
        lg[0] = fmaf(xv[j], wa.x, lg[0]);
        lg[1] = fmaf(xv[j], wa.y, lg[1]);
        lg[2] = fmaf(xv[j], wa.z, lg[2]);
        lg[3] = fmaf(xv[j], wa.w, lg[3]);
        lg[4] = fmaf(xv[j], wb.x, lg[4]);
        lg[5] = fmaf(xv[j], wb.y, lg[5]);
        lg[6] = fmaf(xv[j], wb.z, lg[6]);
        lg[7] = fmaf(xv[j], wb.w, lg[7]);
    }
#pragma unroll
    for (int off = 32; off > 0; off >>= 1) {
#pragma unroll
        for (int e = 0; e < 8; e++) lg[e] += __shfl_xor(lg[e], off, 64);
    }
    float l0 = lg[0]; int i0 = 0;
#pragma unroll
    for (int e = 1; e < 8; e++) { if (lg[e] > l0) { l0 = lg[e]; i0 = e; } }
    float l1 = -3.4e38f;
#pragma unroll
    for (int e = 0; e < 8; e++) { if (e != i0 && lg[e] > l1) l1 = lg[e]; }
    float p1 = expf(l1 - l0);
    float sa = 1.0f / (1.0f + p1);
    if (lane == 0) { s0[t] = sa; s1[t] = p1 * sa; }
}

// ---- batched transpose + f32->bf16: in[b][R][C] -> out[b][C][R], tile 32r x 64c ----
__global__ void transpose_cvt_kernel(const float* __restrict__ in, short* __restrict__ out,
                                     int R, int C) {
    __shared__ float t[64][33];
    int b = blockIdx.z;
    const float* ip = in + (size_t)b * R * C;
    short* op = out + (size_t)b * R * C;
    int c0 = blockIdx.x * 64, r0 = blockIdx.y * 32;
    int tid = threadIdx.x;
    int lr = tid >> 3, lc8 = (tid & 7) * 8;
    const float* src = &ip[(size_t)(r0 + lr) * C + c0 + lc8];
    float4 v0 = *(const float4*)src;
    float4 v1 = *(const float4*)(src + 4);
    t[lc8 + 0][lr] = v0.x; t[lc8 + 1][lr] = v0.y; t[lc8 + 2][lr] = v0.z; t[lc8 + 3][lr] = v0.w;
    t[lc8 + 4][lr] = v1.x; t[lc8 + 5][lr] = v1.y; t[lc8 + 6][lr] = v1.z; t[lc8 + 7][lr] = v1.w;
    __syncthreads();
    int sc = tid >> 2, sk = (tid & 3) * 8;
    s16x8 o;
#pragma unroll
    for (int j = 0; j < 8; j++) o[j] = f2bf(t[sc][sk + j]);
    *(s16x8*)&op[(size_t)(c0 + sc) * R + r0 + sk] = o;
}

// ---- GEMM1 + fused activation: H[e] = gelu(s0*(x@W1[e])+b1) + gelu(s1*(x@W1[e])+b1) ----
__launch_bounds__(256, 2)
__global__ void gemm1_kernel(const short* __restrict__ xb, const short* __restrict__ w1t,
                             const float* __restrict__ s0v, const float* __restrict__ s1v,
                             const float* __restrict__ b1, short* __restrict__ H) {
    __shared__ short Al[128 * 64];
    __shared__ short Bl[128 * 64];
    __shared__ float ls0[128], ls1[128], lb1[128];
    int d = blockIdx.x;
    int e = d & 7;
    int tno = d >> 3;
    int n0 = (tno & 15) * 128;
    int m0 = (tno >> 4) * 128;
    const short* A = xb;
    const short* B = w1t + (size_t)e * DFF * DMODEL;
    short* Ho = H + (size_t)e * TOKENS * DFF;

    int tid = threadIdx.x;
    int lane = tid & 63;
    int w = tid >> 6;
    int m_off = (w >> 1) * 64;
    int n_off = (w & 1) * 64;

    if (tid < 128) {
        ls0[tid] = s0v[m0 + tid];
        ls1[tid] = s1v[m0 + tid];
        lb1[tid] = b1[(size_t)e * DFF + n0 + tid];
    }

    int srow = lane >> 3;
    int schunk = (lane & 7) ^ srow;
    int q = lane >> 4;

    f32x4 acc[4][4];
#pragma unroll
    for (int mi = 0; mi < 4; mi++)
#pragma unroll
        for (int ni = 0; ni < 4; ni++) acc[mi][ni] = (f32x4){0.f, 0.f, 0.f, 0.f};

    for (int k0 = 0; k0 < DMODEL; k0 += 64) {
#pragma unroll
        for (int c = 0; c < 4; c++) {
            int seg = c * 4 + w;
            gload_lds16(&A[(size_t)(m0 + seg * 8 + srow) * DMODEL + k0 + schunk * 8],
                        &Al[seg * 512]);
            gload_lds16(&B[(size_t)(n0 + seg * 8 + srow) * DMODEL + k0 + schunk * 8],
                        &Bl[seg * 512]);
        }
        __syncthreads();
#pragma unroll
        for (int ks = 0; ks < 2; ks++) {
            s16x8 af[4], bfr[4];
#pragma unroll
            for (int mi = 0; mi < 4; mi++) {
                int r = m_off + mi * 16 + (lane & 15);
                int cp = (ks * 4 + q) ^ (r & 7);
                af[mi] = *(const s16x8*)&Al[r * 64 + cp * 8];
            }
#pragma unroll
            for (int ni = 0; ni < 4; ni++) {
                int r = n_off + ni * 16 + (lane & 15);
                int cp = (ks * 4 + q) ^ (r & 7);
                bfr[ni] = *(const s16x8*)&Bl[r * 64 + cp * 8];
            }
#pragma unroll
            for (int mi = 0; mi < 4; mi++)
#pragma unroll
                for (int ni = 0; ni < 4; ni++)
                    acc[mi][ni] = __builtin_amdgcn_mfma_f32_16x16x32_bf16(af[mi], bfr[ni], acc[mi][ni], 0, 0, 0);
        }
        __syncthreads();
    }
    // epilogue: fused dual-gelu on f32 accumulators
#pragma unroll
    for (int mi = 0; mi < 4; mi++) {
        int rl = m_off + mi * 16 + (lane >> 4) * 4;
        float sa4[4], sb4[4];
#pragma unroll
        for (int r = 0; r < 4; r++) { sa4[r] = ls0[rl + r]; sb4[r] = ls1[rl + r]; }
#pragma unroll
        for (int ni = 0; ni < 4; ni++) {
            int cl = n_off + ni * 16 + (lane & 15);
            float bb = lb1[cl];
#pragma unroll
            for (int r = 0; r < 4; r++) {
                float a = acc[mi][ni][r];
                float h = gelu_f(fmaf(sa4[r], a, bb)) + gelu_f(fmaf(sb4[r], a, bb));
                Ho[(size_t)(m0 + rl + r) * DFF + n0 + cl] = f2bf(h);
            }
        }
    }
}

// ------- GEMM2 (pure): part[e] = H[e] @ W2[e]  (128x128 tile, BK=64, 4 waves) -------
__launch_bounds__(256, 2)
__global__ void gemm2_kernel(const short* __restrict__ H, const short* __restrict__ w2t,
                             float* __restrict__ part) {
    __shared__ short Al[128 * 64];
    __shared__ short Bl[128 * 64];
    int d = blockIdx.x;
    int e = d & 7;                   // expert -> XCD pin
    int tno = d >> 3;                // 0..127
    int n0 = (tno & 3) * 128;
    int m0 = (tno >> 2) * 128;
    const short* A = H + (size_t)e * TOKENS * DFF;     // [4096][2048]
    const short* B = w2t + (size_t)e * DMODEL * DFF;   // [512][2048] = W2^T
    float* Pe = part + (size_t)e * TOKENS * DMODEL;

    int tid = threadIdx.x;
    int lane = tid & 63;
    int w = tid >> 6;
    int m_off = (w >> 1) * 64;
    int n_off = (w & 1) * 64;

    int srow = lane >> 3;
    int schunk = (lane & 7) ^ srow;
    int q = lane >> 4;

    f32x4 acc[4][4];
#pragma unroll
    for (int mi = 0; mi < 4; mi++)
#pragma unroll
        for (int ni = 0; ni < 4; ni++) acc[mi][ni] = (f32x4){0.f, 0.f, 0.f, 0.f};

    for (int k0 = 0; k0 < DFF; k0 += 64) {
#pragma unroll
        for (int c = 0; c < 4; c++) {
            int seg = c * 4 + w;
            gload_lds16(&A[(size_t)(m0 + seg * 8 + srow) * DFF + k0 + schunk * 8],
                        &Al[seg * 512]);
            gload_lds16(&B[(size_t)(n0 + seg * 8 + srow) * DFF + k0 + schunk * 8],
                        &Bl[seg * 512]);
        }
        __syncthreads();
#pragma unroll
        for (int ks = 0; ks < 2; ks++) {
            s16x8 af[4], bfr[4];
#pragma unroll
            for (int mi = 0; mi < 4; mi++) {
                int r = m_off + mi * 16 + (lane & 15);
                int cp = (ks * 4 + q) ^ (r & 7);
                af[mi] = *(const s16x8*)&Al[r * 64 + cp * 8];
            }
#pragma unroll
            for (int ni = 0; ni < 4; ni++) {
                int r = n_off + ni * 16 + (lane & 15);
                int cp = (ks * 4 + q) ^ (r & 7);
                bfr[ni] = *(const s16x8*)&Bl[r * 64 + cp * 8];
            }
#pragma unroll
            for (int mi = 0; mi < 4; mi++)
#pragma unroll
                for (int ni = 0; ni < 4; ni++)
                    acc[mi][ni] = __builtin_amdgcn_mfma_f32_16x16x32_bf16(af[mi], bfr[ni], acc[mi][ni], 0, 0, 0);
        }
        __syncthreads();
    }

#pragma unroll
    for (int mi = 0; mi < 4; mi++)
#pragma unroll
        for (int ni = 0; ni < 4; ni++) {
            int row = m0 + m_off + mi * 16 + (lane >> 4) * 4;
            int col = n0 + n_off + ni * 16 + (lane & 15);
#pragma unroll
            for (int r = 0; r < 4; r++)
                Pe[(size_t)(row + r) * DMODEL + col] = acc[mi][ni][r];
        }
}

// ---------------- reduce over experts + 2*b2_sum ----------------
__global__ void reduce_kernel(const float* __restrict__ part, const float* __restrict__ b2,
                              float* __restrict__ out) {
    int i = (blockIdx.x * 256 + threadIdx.x) * 4;
    if (i >= TOKENS * DMODEL) return;
    int n = i & (DMODEL - 1);
    float4 s = {0.f, 0.f, 0.f, 0.f};
    float4 bs = {0.f, 0.f, 0.f, 0.f};
#pragma unroll
    for (int e = 0; e < 8; e++) {
        float4 p = *(const float4*)&part[(size_t)e * TOKENS * DMODEL + i];
        s.x += p.x; s.y += p.y; s.z += p.z; s.w += p.w;
        float4 b = *(const float4*)&b2[(size_t)e * DMODEL + n];
        bs.x += b.x; bs.y += b.y; bs.z += b.z; bs.w += b.w;
    }
    s.x += 2.f * bs.x; s.y += 2.f * bs.y; s.z += 2.f * bs.z; s.w += 2.f * bs.w;
    *(float4*)&out[i] = s;
}

extern "C" void kernel_launch(void* const* d_in, const int* in_sizes, int n_in,
                              void* d_out, int out_size, void* d_ws, size_t ws_size,
                              hipStream_t stream) {
    const float* x  = (const float*)d_in[0];
    const float* Wg = (const float*)d_in[1];
    const float* W1 = (const float*)d_in[2];
    const float* b1 = (const float*)d_in[3];
    const float* W2 = (const float*)d_in[4];
    const float* b2 = (const float*)d_in[5];
    float* out = (float*)d_out;

    char* ws = (char*)d_ws;
    float* s0  = (float*)(ws);
    float* s1  = (float*)(ws + 16384);
    short* xb  = (short*)(ws + 32768);
    short* w1t = (short*)(ws + 32768 + 4194304);
    short* w2t = (short*)(ws + 32768 + 4194304 + 16777216);
    short* Hb  = (short*)(ws + 32768 + 4194304 + 2ull * 16777216);              // 128MB [e][4096][2048]
    float* part= (float*)(ws + 32768 + 4194304 + 2ull * 16777216 + 134217728);  // 64MB

    hipLaunchKernelGGL(gate_cvt_kernel, dim3(1024), dim3(256), 0, stream, x, Wg, s0, s1, xb);
    hipLaunchKernelGGL(transpose_cvt_kernel, dim3(32, 16, 8), dim3(256), 0, stream, W1, w1t, 512, 2048);
    hipLaunchKernelGGL(transpose_cvt_kernel, dim3(8, 64, 8), dim3(256), 0, stream, W2, w2t, 2048, 512);
    hipLaunchKernelGGL(gemm1_kernel, dim3(4096), dim3(256), 0, stream, xb, w1t, s0, s1, b1, Hb);
    hipLaunchKernelGGL(gemm2_kernel, dim3(1024), dim3(256), 0, stream, Hb, w2t, part);
    hipLaunchKernelGGL(reduce_kernel, dim3(2048), dim3(256), 0, stream, part, b2, out);
}